// Round 18
// baseline (10120.005 us; speedup 1.0000x reference)
//
#include <hip/hip_runtime.h>
#include <math.h>

// ---------------- problem dims ----------------
#define VV 32000
#define HH 512
#define G3 1536   // 3*HH
#define TI 128    // encoder length
#define TO 64     // max decode length
#define NB 5      // beam width
#define NEGF (-1000000000.0f)
#define NTHR 256
#define LSTR 32   // words per counter/flag line (128B)

struct Params {
  const int* seq;
  const int* sosp;
  const float *emb, *eWi, *eWh, *ebi, *ebh;
  const float *dWi, *dWh, *dbi, *dbh;
  const float *Wc, *bc, *Wout, *bout;
  unsigned* bar;
  int *cur_tok, *toks, *pars, *ptop_i;
  float *gi0, *eout, *h0b, *h1b, *dch, *cc, *ptop_v, *psum, *scores;
  float* out;
};

// relaxed agent-scope (coherence-point) ops for INTRA-kernel cross-WG data
__device__ __forceinline__ float cldf(const float* p) {
  return __hip_atomic_load(p, __ATOMIC_RELAXED, __HIP_MEMORY_SCOPE_AGENT);
}
__device__ __forceinline__ void cstf(float* p, float v) {
  __hip_atomic_store(p, v, __ATOMIC_RELAXED, __HIP_MEMORY_SCOPE_AGENT);
}
__device__ __forceinline__ int cldi(const int* p) {
  return __hip_atomic_load(p, __ATOMIC_RELAXED, __HIP_MEMORY_SCOPE_AGENT);
}
__device__ __forceinline__ void csti(int* p, int v) {
  __hip_atomic_store(p, v, __ATOMIC_RELAXED, __HIP_MEMORY_SCOPE_AGENT);
}
__device__ __forceinline__ unsigned rldu(const unsigned* p) {
  return __hip_atomic_load(p, __ATOMIC_RELAXED, __HIP_MEMORY_SCOPE_AGENT);
}
typedef unsigned long long u64t;
union F2U { u64t u; float f[2]; };
__device__ __forceinline__ void cld2(float* d, const float* p) {
  F2U x; x.u = __hip_atomic_load((const u64t*)p, __ATOMIC_RELAXED, __HIP_MEMORY_SCOPE_AGENT);
  d[0] = x.f[0]; d[1] = x.f[1];
}

__device__ __forceinline__ void bar_arrive(unsigned* lines, int myline) {
  __syncthreads();  // all this WG's sc-stores vm-drained (at CP)
  if (threadIdx.x == 0)
    __hip_atomic_fetch_add(lines + myline * LSTR, 1u,
                           __ATOMIC_RELAXED, __HIP_MEMORY_SCOPE_AGENT);
}
template <int SLP>
__device__ __forceinline__ void bar_wait8(const unsigned* lines, unsigned tgt) {
  if (threadIdx.x < 64) {
    for (;;) {
      unsigned v = tgt;
      if (threadIdx.x < 8) v = rldu(lines + threadIdx.x * LSTR);
      if (__all(v >= tgt)) break;
      __builtin_amdgcn_s_sleep(SLP);
    }
  }
  __syncthreads();
}
__device__ __forceinline__ void bcast_store(unsigned* L, int NL, unsigned tok) {
  asm volatile("s_waitcnt vmcnt(0)" ::: "memory");
  for (int i = 0; i < NL; i++)
    __hip_atomic_store(L + i * LSTR, tok, __ATOMIC_RELAXED, __HIP_MEMORY_SCOPE_AGENT);
}
template <int SLP>
__device__ __forceinline__ void leaf_wait(const unsigned* L, int grp, unsigned tok) {
  if (threadIdx.x == 0) {
    while (rldu(L + grp * LSTR) < tok) __builtin_amdgcn_s_sleep(SLP);
  }
  __syncthreads();
}

__device__ __forceinline__ float wredf(float v) {
#pragma unroll
  for (int o = 32; o; o >>= 1) v += __shfl_xor(v, o, 64);
  return v;
}

// ========== E0: wave-parallel over t (r14-validated) ==========
__global__ void __launch_bounds__(NTHR) k_e0(Params p) {
  const int wg = blockIdx.x, tid = threadIdx.x;
  const int lane = tid & 63, wv = tid >> 6;
  if (wg == 0) {
    for (int i = tid; i < 2 * HH; i += NTHR) { cstf(&p.h0b[i], 0.f); cstf(&p.h1b[i], 0.f); }
  }
  for (int lr = 0; lr < 6; lr++) {
    int row = wg * 6 + lr;
    const float* W = p.eWi + (size_t)row * HH;
    float w0[8];
#pragma unroll
    for (int j = 0; j < 8; j++) w0[j] = W[j * 64 + lane];
    float bi = p.ebi[row];
    for (int t = wv; t < TI; t += 4) {
      const float* x = p.emb + (size_t)p.seq[t] * HH;
      float s = 0.f;
#pragma unroll
      for (int j = 0; j < 8; j++) s += w0[j] * x[j * 64 + lane];
      s = wredf(s);
      if (lane == 0) p.gi0[(size_t)t * G3 + row] = s + bi;
    }
  }
}

// one encoder diagonal step (r13-validated, 64 WGs, 8 units/WG)
__device__ void enc_step(const Params& p, int T, int wg, int lane, int wv) {
  const int sIn = T & 1, sOut = sIn ^ 1;
  if (wv < 2) {
    if (T < TI) {
      float hv[8];
#pragma unroll
      for (int j = 0; j < 8; j++) hv[j] = cldf(&p.h0b[sIn * HH + j * 64 + lane]);
#pragma unroll
      for (int uu = 0; uu < 4; uu++) {
        int u = wg * 8 + wv * 4 + uu;
        float g[3];
#pragma unroll
        for (int gg = 0; gg < 3; gg++) {
          const float* W = p.eWh + (size_t)(gg * HH + u) * HH;
          float s = 0.f;
#pragma unroll
          for (int j = 0; j < 8; j++) s += W[j * 64 + lane] * hv[j];
          g[gg] = wredf(s);
        }
        if (lane == 0) {
          const float* gr = p.gi0 + (size_t)T * G3;  // plain cached (immutable)
          float ir = gr[u], iz = gr[HH + u], inn = gr[2 * HH + u];
          float hr = g[0] + p.ebh[u], hz = g[1] + p.ebh[HH + u], hn = g[2] + p.ebh[2 * HH + u];
          float r = 1.f / (1.f + expf(-(ir + hr)));
          float z = 1.f / (1.f + expf(-(iz + hz)));
          float n = tanhf(inn + r * hn);
          float hp = cldf(&p.h0b[sIn * HH + u]);
          cstf(&p.h0b[sOut * HH + u], (1.f - z) * n + z * hp);
        }
      }
    }
  } else {
    if (T >= 1) {
      float xv[8], hv[8];
#pragma unroll
      for (int j = 0; j < 8; j++) {
        xv[j] = cldf(&p.h0b[sIn * HH + j * 64 + lane]);
        hv[j] = cldf(&p.h1b[sOut * HH + j * 64 + lane]);
      }
#pragma unroll
      for (int uu = 0; uu < 4; uu++) {
        int u = wg * 8 + (wv - 2) * 4 + uu;
        float gi[3], gh[3];
#pragma unroll
        for (int gg = 0; gg < 3; gg++) {
          const float* Wi1 = p.eWi + (size_t)G3 * HH + (size_t)(gg * HH + u) * HH;
          const float* Wh1 = p.eWh + (size_t)G3 * HH + (size_t)(gg * HH + u) * HH;
          float si = 0.f, s2 = 0.f;
#pragma unroll
          for (int j = 0; j < 8; j++) { si += Wi1[j * 64 + lane] * xv[j]; s2 += Wh1[j * 64 + lane] * hv[j]; }
          gi[gg] = wredf(si);
          gh[gg] = wredf(s2);
        }
        if (lane == 0) {
          const float* bi = p.ebi + G3;
          const float* bh = p.ebh + G3;
          float ir = gi[0] + bi[u], iz = gi[1] + bi[HH + u], inn = gi[2] + bi[2 * HH + u];
          float hr = gh[0] + bh[u], hz = gh[1] + bh[HH + u], hn = gh[2] + bh[2 * HH + u];
          float r = 1.f / (1.f + expf(-(ir + hr)));
          float z = 1.f / (1.f + expf(-(iz + hz)));
          float n = tanhf(inn + r * hn);
          float hp = cldf(&p.h1b[sOut * HH + u]);
          float hnew = (1.f - z) * n + z * hp;
          cstf(&p.h1b[sIn * HH + u], hnew);
          p.eout[(size_t)(T - 1) * HH + u] = hnew;  // plain: flushed at node end
        }
      }
    }
  }
}

// node k: steps T=2k, 2k+1 with one internal leg (r13-validated)
__global__ void __launch_bounds__(NTHR) k_e1x2(Params p, int k) {
  const int wg = blockIdx.x, tid = threadIdx.x;
  const int lane = tid & 63, wv = tid >> 6;
  unsigned* ceA = p.bar + 0 * LSTR;
  enc_step(p, 2 * k, wg, lane, wv);
  if (2 * k + 1 <= TI) {
    bar_arrive(ceA, wg & 7);
    bar_wait8<2>(ceA, (unsigned)(8 * (k + 1)));
    enc_step(p, 2 * k + 1, wg, lane, wv);
  }
}

// ========== D0 (r13-validated) ==========
__global__ void __launch_bounds__(NTHR) k_d0(Params p) {
  const int wg = blockIdx.x, tid = threadIdx.x;
  for (int i = tid + wg * NTHR; i < 2 * NB * HH; i += 64 * NTHR) {
    int l = i / (NB * HH);
    int rem = i - l * (NB * HH);
    int u = rem % HH;
    p.dch[(size_t)l * NB * HH + rem] = (l == 0) ? cldf(&p.h0b[u]) : cldf(&p.h1b[u]);
  }
  if (wg == 0 && tid < NB) {
    p.cur_tok[tid] = p.sosp[0];
    p.scores[tid] = (tid == 0) ? 0.f : NEGF;
  }
}

// decoder GRU layer body on 64 WGs (r13-validated); dch via sc ops
template <int LAYER>
__device__ void gru_body(const Params& p, float* sm, int t, int ib, int ob,
                         int wg, int tid, int lane, int wv) {
  float* sx = sm;                 // [NB][HH]
  float* sh = sm + NB * HH;       // [NB][HH]
  float* fres = sm + 2 * NB * HH; // [48][NB]
  int ct[NB], pr[NB];
#pragma unroll
  for (int b = 0; b < NB; b++) {
    ct[b] = (LAYER == 0) ? cldi(&p.cur_tok[b]) : 0;
    pr[b] = (t == 0) ? b : cldi(&p.pars[(t - 1) * NB + b]);
  }
  for (int i = tid; i < NB * (HH / 2); i += NTHR) {
    int b = i >> 8, c = (i & 255) << 1;
    float x2[2], h2[2];
    if (LAYER == 0) {
      const float* e = p.emb + (size_t)ct[b] * HH + c;
      x2[0] = e[0]; x2[1] = e[1];
    } else {
      cld2(x2, &p.dch[((size_t)(ob * 2 + 0) * NB + b) * HH + c]);
    }
    cld2(h2, &p.dch[((size_t)(ib * 2 + LAYER) * NB + pr[b]) * HH + c]);
    sx[b * HH + c] = x2[0]; sx[b * HH + c + 1] = x2[1];
    sh[b * HH + c] = h2[0]; sh[b * HH + c + 1] = h2[1];
  }
  __syncthreads();
  const float* Wi = p.dWi + (size_t)LAYER * G3 * HH;
  const float* Wh = p.dWh + (size_t)LAYER * G3 * HH;
#pragma unroll
  for (int k = 0; k < 12; k++) {
    const int m_ = k % 6;
    const int f = wv * 12 + k;
    const int ul = f / 6;
    const int u = wg * 8 + ul;
    const float* W = (m_ >= 3 ? Wh : Wi) + (size_t)((m_ % 3) * HH + u) * HH;
    const float* vecb = (m_ >= 3) ? sh : sx;
    float wd[8];
#pragma unroll
    for (int j = 0; j < 8; j++) wd[j] = W[j * 64 + lane];
    float a0 = 0.f, a1 = 0.f, a2 = 0.f, a3 = 0.f, a4 = 0.f;
#pragma unroll
    for (int j = 0; j < 8; j++) {
      float wj = wd[j];
      int o = j * 64 + lane;
      a0 += wj * vecb[0 * HH + o];
      a1 += wj * vecb[1 * HH + o];
      a2 += wj * vecb[2 * HH + o];
      a3 += wj * vecb[3 * HH + o];
      a4 += wj * vecb[4 * HH + o];
    }
    float r0 = wredf(a0), r1 = wredf(a1), r2 = wredf(a2), r3 = wredf(a3), r4 = wredf(a4);
    if (lane == 0) {
      fres[f * NB + 0] = r0; fres[f * NB + 1] = r1; fres[f * NB + 2] = r2;
      fres[f * NB + 3] = r3; fres[f * NB + 4] = r4;
    }
  }
  __syncthreads();
  if (tid < 8 * NB) {
    int ul = tid / NB, b = tid - ul * NB;
    int u = wg * 8 + ul;
    const float* bi = p.dbi + LAYER * G3;
    const float* bh = p.dbh + LAYER * G3;
    float ir = fres[(ul * 6 + 0) * NB + b] + bi[u];
    float iz = fres[(ul * 6 + 1) * NB + b] + bi[HH + u];
    float inn = fres[(ul * 6 + 2) * NB + b] + bi[2 * HH + u];
    float hr = fres[(ul * 6 + 3) * NB + b] + bh[u];
    float hz = fres[(ul * 6 + 4) * NB + b] + bh[HH + u];
    float hn = fres[(ul * 6 + 5) * NB + b] + bh[2 * HH + u];
    float hp = sh[b * HH + u];
    float r = 1.f / (1.f + expf(-(ir + hr)));
    float z = 1.f / (1.f + expf(-(iz + hz)));
    float n = tanhf(inn + r * hn);
    cstf(&p.dch[((size_t)(ob * 2 + LAYER) * NB + b) * HH + u], (1.f - z) * n + z * hp);
  }
  __syncthreads();
}

// fused GRU0 + 64-WG leg + GRU1 (r13-validated)
__global__ void __launch_bounds__(NTHR) k_gru2(Params p, int t) {
  const int wg = blockIdx.x, tid = threadIdx.x;
  const int lane = tid & 63, wv = tid >> 6;
  const int ib = t & 1, ob = ib ^ 1;
  __shared__ float sm[2 * NB * HH + 48 * NB];
  unsigned* gruA = p.bar + 8 * LSTR;
  gru_body<0>(p, sm, t, ib, ob, wg, tid, lane, wv);
  bar_arrive(gruA, wg & 7);
  bar_wait8<2>(gruA, (unsigned)(8 * (t + 1)));
  gru_body<1>(p, sm, t, ib, ob, wg, tid, lane, wv);
}

// fused PA (wg<40, while wg>=40 WARM their Wout chunk) + leg +
// P5 (reg-scc, float4, 3-deep prefetch) + last-man P6 (+backtrack)
__global__ void __launch_bounds__(NTHR) k_pa56(Params p, int t) {
  const int wg = blockIdx.x, tid = threadIdx.x;
  const int lane = tid & 63, wv = tid >> 6;
  const int ob = (t & 1) ^ 1;
  __shared__ float sm[3200];
  __shared__ unsigned s_mrg;
  unsigned* paA = p.bar + 16 * LSTR;  // 8
  unsigned* paF = p.bar + 24 * LSTR;  // 1
  unsigned* paL = p.bar + 32 * LSTR;  // 16 (lines 32-47)
  unsigned* c5A = p.bar + 48 * LSTR;  // 8
  unsigned* c5F = p.bar + 56 * LSTR;  // 1

  if (wg >= 40) {
    // WARM: stream this WG's own Wout chunk into its CU's L2 (and L3) while
    // the 40 PA WGs compute attention. Same WG -> same CU/XCD as the P5 phase
    // below, so the warmed lines are local. Sum keeps loads live.
    const float4* W4 = (const float4*)(p.Wout + (size_t)wg * 125 * HH);
    float acc = 0.f;
    for (int i = tid; i < 125 * (HH / 4); i += NTHR) {
      float4 v = W4[i];
      acc += (v.x + v.y) + (v.z + v.w);
    }
    if (acc == 123.456789f) *((float*)(p.bar + 58 * LSTR)) = acc;  // never true
  } else {
    const int b = wg / 8, q = wg % 8;
    float* srnn = sm;            // 512
    float* sp = sm + 512;        // 128
    float* cpart = sm + 640;     // [4][512]
    float* sctx = sm + 2688;     // 512
    for (int i = tid; i < HH; i += NTHR)
      srnn[i] = cldf(&p.dch[((size_t)(ob * 2 + 1) * NB + b) * HH + i]);
    __syncthreads();
    for (int j = wv; j < TI; j += 4) {
      const float* E = p.eout + (size_t)j * HH;  // plain cached (immutable)
      float s = 0.f;
#pragma unroll
      for (int k2 = 0; k2 < 8; k2++) s += srnn[k2 * 64 + lane] * E[k2 * 64 + lane];
      s = wredf(s);
      if (lane == 0) sp[j] = s;
    }
    __syncthreads();
    if (wv == 0) {
      float v0 = sp[lane], v1 = sp[64 + lane];
      float mx = fmaxf(v0, v1);
#pragma unroll
      for (int o = 32; o; o >>= 1) mx = fmaxf(mx, __shfl_xor(mx, o, 64));
      float e0 = expf(v0 - mx), e1 = expf(v1 - mx);
      float ss = wredf(e0 + e1);
      sp[lane] = e0 / ss;
      sp[64 + lane] = e1 / ss;
    }
    __syncthreads();
    {
      float cp[8];
#pragma unroll
      for (int k2 = 0; k2 < 8; k2++) cp[k2] = 0.f;
      for (int j = wv; j < TI; j += 4) {
        float spj = sp[j];
        const float* E = p.eout + (size_t)j * HH;
#pragma unroll
        for (int k2 = 0; k2 < 8; k2++) cp[k2] += spj * E[k2 * 64 + lane];
      }
#pragma unroll
      for (int k2 = 0; k2 < 8; k2++) cpart[wv * HH + k2 * 64 + lane] = cp[k2];
    }
    __syncthreads();
    for (int i = tid; i < HH; i += NTHR)
      sctx[i] = ((cpart[0 * HH + i] + cpart[1 * HH + i]) + cpart[2 * HH + i]) + cpart[3 * HH + i];
    __syncthreads();
    for (int k = wv; k < 64; k += 4) {
      int u = q * 64 + k;
      const float* W = p.Wc + (size_t)u * (2 * HH);
      float s0 = 0.f, s1 = 0.f;
#pragma unroll
      for (int j = 0; j < 8; j++) {
        int o = j * 64 + lane;
        s0 += W[o] * srnn[o];
        s1 += W[HH + o] * sctx[o];
      }
      float r0 = wredf(s0), r1 = wredf(s1);
      if (lane == 0) cstf(&p.cc[b * HH + u], tanhf(r0 + r1 + p.bc[u]));
    }
    // last-man over PA -> bcast paL
    __syncthreads();
    if (tid == 0) {
      unsigned o1 = __hip_atomic_fetch_add(paA + (wg & 7) * LSTR, 1u,
                                           __ATOMIC_RELAXED, __HIP_MEMORY_SCOPE_AGENT);
      if (o1 == (unsigned)(5 * (t + 1) - 1)) {
        unsigned o2 = __hip_atomic_fetch_add(paF, 1u,
                                             __ATOMIC_RELAXED, __HIP_MEMORY_SCOPE_AGENT);
        if (o2 == (unsigned)(8 * (t + 1) - 1))
          bcast_store(paL, 16, (unsigned)(t + 1));
      }
    }
  }
  leaf_wait<4>(paL, wg >> 4, (unsigned)(t + 1));

  // ---- P5: logits (125 rows/WG); scc in REGISTERS, float4 W, 3-deep prefetch.
  // Dot grouping differs from r13 (lane owns 8 consecutive elems): logits move
  // by ~1e-6 relative -- far inside the 588.8 threshold and the ~1e-2 top-5 gaps.
  {
    float* scc = sm;            // [NB][HH]
    float* slg = sm + NB * HH;  // [NB][125]
    for (int i = tid; i < NB * (HH / 2); i += NTHR) {
      int b = i >> 8, c = (i & 255) << 1;
      float c2v[2];
      cld2(c2v, &p.cc[b * HH + c]);
      scc[b * HH + c] = c2v[0]; scc[b * HH + c + 1] = c2v[1];
    }
    __syncthreads();
    float sr[NB][8];
#pragma unroll
    for (int b = 0; b < NB; b++)
#pragma unroll
      for (int jj = 0; jj < 8; jj++) sr[b][jj] = scc[b * HH + lane * 8 + jj];

    const int vbase = wg * 125;
    const float4* W4 = (const float4*)(p.Wout + (size_t)vbase * HH);
    float4 A0 = {0,0,0,0}, A1 = {0,0,0,0}, B0 = {0,0,0,0}, B1 = {0,0,0,0},
           C0 = {0,0,0,0}, C1 = {0,0,0,0};
    {
      int r0_ = wv, r1_ = wv + 4, r2_ = wv + 8;
      A0 = W4[(size_t)r0_ * 128 + lane * 2]; A1 = W4[(size_t)r0_ * 128 + lane * 2 + 1];
      if (r1_ < 125) { B0 = W4[(size_t)r1_ * 128 + lane * 2]; B1 = W4[(size_t)r1_ * 128 + lane * 2 + 1]; }
      if (r2_ < 125) { C0 = W4[(size_t)r2_ * 128 + lane * 2]; C1 = W4[(size_t)r2_ * 128 + lane * 2 + 1]; }
    }
    for (int r = wv; r < 125; r += 4) {
      float a[NB];
#pragma unroll
      for (int b = 0; b < NB; b++) {
        a[b] = ((A0.x * sr[b][0] + A0.y * sr[b][1]) + (A0.z * sr[b][2] + A0.w * sr[b][3]))
             + ((A1.x * sr[b][4] + A1.y * sr[b][5]) + (A1.z * sr[b][6] + A1.w * sr[b][7]));
      }
      A0 = B0; A1 = B1; B0 = C0; B1 = C1;
      if (r + 12 < 125) {
        C0 = W4[(size_t)(r + 12) * 128 + lane * 2];
        C1 = W4[(size_t)(r + 12) * 128 + lane * 2 + 1];
      }
      float r0 = wredf(a[0]), r1 = wredf(a[1]), r2 = wredf(a[2]), r3 = wredf(a[3]), r4 = wredf(a[4]);
      if (lane == 0) {
        float bo = p.bout[vbase + r];
        slg[0 * 125 + r] = r0 + bo;
        slg[1 * 125 + r] = r1 + bo;
        slg[2 * 125 + r] = r2 + bo;
        slg[3 * 125 + r] = r3 + bo;
        slg[4 * 125 + r] = r4 + bo;
      }
    }
    __syncthreads();
    if (wv == 0) {
      for (int b = 0; b < NB; b++) {
        float s0 = (lane < 125) ? expf(slg[b * 125 + lane]) : 0.f;
        float s1 = (lane + 64 < 125) ? expf(slg[b * 125 + lane + 64]) : 0.f;
        float ss = wredf(s0 + s1);
        if (lane == 0) cstf(&p.psum[wg * NB + b], ss);
      }
    } else if (wv == 1 && lane < NB) {
      int b = lane;
      float bv[5]; int bidx[5];
#pragma unroll
      for (int k = 0; k < 5; k++) { bv[k] = -INFINITY; bidx[k] = 0x7fffffff; }
      for (int r = 0; r < 125; r++) {
        float v = slg[b * 125 + r];
        if (v > bv[4]) {  // strict >: equal values keep earlier (lower) index
          int k = 4;
          while (k > 0 && v > bv[k - 1]) { bv[k] = bv[k - 1]; bidx[k] = bidx[k - 1]; k--; }
          bv[k] = v; bidx[k] = vbase + r;
        }
      }
#pragma unroll
      for (int k = 0; k < 5; k++) {
        cstf(&p.ptop_v[(wg * NB + b) * 5 + k], bv[k]);
        csti(&p.ptop_i[(wg * NB + b) * 5 + k], bidx[k]);
      }
    }
  }

  // ---- last-man selection: final P5 arriver performs the merge ----
  __syncthreads();
  if (tid == 0) {
    unsigned m = 0;
    unsigned o1 = __hip_atomic_fetch_add(c5A + (wg & 7) * LSTR, 1u,
                                         __ATOMIC_RELAXED, __HIP_MEMORY_SCOPE_AGENT);
    if (o1 == (unsigned)(32 * (t + 1) - 1)) {
      unsigned o2 = __hip_atomic_fetch_add(c5F, 1u,
                                           __ATOMIC_RELAXED, __HIP_MEMORY_SCOPE_AGENT);
      if (o2 == (unsigned)(8 * (t + 1) - 1)) m = 1;
    }
    s_mrg = m;
  }
  __syncthreads();

  // ---- P6 merge (single last-arriving WG; r10-validated algorithm) ----
  if (s_mrg) {
    float* sls = sm;               // [5]
    float* smv = sm + 8;           // [5][5]
    int* smi = (int*)(sm + 40);    // [5][5]
    for (int b = wv; b < NB; b += 4) {
      float q0 = cldf(&p.psum[(lane + 0) * NB + b]);
      float q1 = cldf(&p.psum[(lane + 64) * NB + b]);
      float q2 = cldf(&p.psum[(lane + 128) * NB + b]);
      float q3 = cldf(&p.psum[(lane + 192) * NB + b]);
      float ssum = wredf((q0 + q1) + (q2 + q3));
      float bv[5]; int bix[5];
#pragma unroll
      for (int k = 0; k < 5; k++) { bv[k] = -INFINITY; bix[k] = 0x7fffffff; }
      for (int g = 0; g < 4; g++) {
        int w = lane + g * 64;
#pragma unroll
        for (int k = 0; k < 5; k++) {
          float v = cldf(&p.ptop_v[((size_t)w * NB + b) * 5 + k]);
          int id = cldi(&p.ptop_i[((size_t)w * NB + b) * 5 + k]);
          if (v > bv[4] || (v == bv[4] && id < bix[4])) {
            int kk = 4;
            while (kk > 0 && (v > bv[kk - 1] || (v == bv[kk - 1] && id < bix[kk - 1]))) {
              bv[kk] = bv[kk - 1]; bix[kk] = bix[kk - 1]; kk--;
            }
            bv[kk] = v; bix[kk] = id;
          }
        }
      }
#pragma unroll
      for (int off = 1; off < 64; off <<= 1) {
        float ov[5]; int oi[5];
#pragma unroll
        for (int k = 0; k < 5; k++) { ov[k] = __shfl_xor(bv[k], off, 64); oi[k] = __shfl_xor(bix[k], off, 64); }
        float nv[5]; int ni[5];
        int i2 = 0, j2 = 0;
#pragma unroll
        for (int k = 0; k < 5; k++) {
          bool ta = (bv[i2] > ov[j2]) || (bv[i2] == ov[j2] && bix[i2] < oi[j2]);
          if (ta) { nv[k] = bv[i2]; ni[k] = bix[i2]; i2++; }
          else { nv[k] = ov[j2]; ni[k] = oi[j2]; j2++; }
        }
#pragma unroll
        for (int k = 0; k < 5; k++) { bv[k] = nv[k]; bix[k] = ni[k]; }
      }
      if (lane == 0) {
        sls[b] = logf(ssum);
#pragma unroll
        for (int k = 0; k < 5; k++) { smv[b * 5 + k] = bv[k]; smi[b * 5 + k] = bix[k]; }
      }
    }
    __syncthreads();
    if (tid == 0) {
      float cand[25]; int ctok[25];
      for (int b = 0; b < NB; b++) {
        float sb = cldf(&p.scores[b]), lb = sls[b];
#pragma unroll
        for (int k = 0; k < 5; k++) {
          cand[b * 5 + k] = sb + (smv[b * 5 + k] - lb);
          ctok[b * 5 + k] = smi[b * 5 + k];
        }
      }
      float s5[5]; int f5[5];
#pragma unroll
      for (int k = 0; k < 5; k++) { s5[k] = -INFINITY; f5[k] = 0x7fffffff; }
      for (int f = 0; f < 25; f++) {
        float v = cand[f];
        if (v > s5[4]) {
          int k = 4;
          while (k > 0 && v > s5[k - 1]) { s5[k] = s5[k - 1]; f5[k] = f5[k - 1]; k--; }
          s5[k] = v; f5[k] = f;
        }
      }
      for (int j2 = 0; j2 < 5; j2++) {
        int fl = f5[j2];
        csti(&p.pars[t * NB + j2], fl / 5);
        csti(&p.toks[t * NB + j2], ctok[fl]);
        csti(&p.cur_tok[j2], ctok[fl]);
      }
      for (int j2 = 0; j2 < 5; j2++) cstf(&p.scores[j2], s5[j2]);
      if (t == TO - 1) {  // final backtrack fused here
        int best = 0;
        float bvv = s5[0];
        for (int j = 1; j < NB; j++)
          if (s5[j] > bvv) { bvv = s5[j]; best = j; }
        int beam = best;
        for (int tt = TO - 1; tt >= 0; tt--) {
          p.out[tt] = (float)cldi(&p.toks[tt * NB + beam]);
          beam = cldi(&p.pars[tt * NB + beam]);
        }
        p.out[TO] = bvv;
      }
    }
  }
}

extern "C" void kernel_launch(void* const* d_in, const int* in_sizes, int n_in,
                              void* d_out, int out_size, void* d_ws, size_t ws_size,
                              hipStream_t stream) {
  (void)in_sizes; (void)n_in; (void)out_size; (void)ws_size;
  Params p;
  p.seq  = (const int*)d_in[0];
  p.sosp = (const int*)d_in[3];
  p.emb  = (const float*)d_in[4];
  p.eWi  = (const float*)d_in[5];
  p.eWh  = (const float*)d_in[6];
  p.ebi  = (const float*)d_in[7];
  p.ebh  = (const float*)d_in[8];
  p.dWi  = (const float*)d_in[9];
  p.dWh  = (const float*)d_in[10];
  p.dbi  = (const float*)d_in[11];
  p.dbh  = (const float*)d_in[12];
  p.Wc   = (const float*)d_in[13];
  p.bc   = (const float*)d_in[14];
  p.Wout = (const float*)d_in[15];
  p.bout = (const float*)d_in[16];

  char* w = (char*)d_ws;
  size_t off = 0;
  auto alloc = [&](size_t words) -> char* {
    char* r = w + off;
    off += words * 4;
    off = (off + 255) & ~(size_t)255;
    return r;
  };
  p.bar     = (unsigned*)alloc(64 * LSTR);    // counter/flag lines (memset below)
  p.cur_tok = (int*)alloc(8);
  p.toks    = (int*)alloc(TO * NB);
  p.pars    = (int*)alloc(TO * NB);
  p.ptop_i  = (int*)alloc(256 * NB * 5);
  p.gi0     = (float*)alloc((size_t)TI * G3);
  p.eout    = (float*)alloc((size_t)TI * HH);
  p.h0b     = (float*)alloc(2 * HH);
  p.h1b     = (float*)alloc(2 * HH);
  p.dch     = (float*)alloc(2 * 2 * NB * HH);
  p.cc      = (float*)alloc(NB * HH);
  p.ptop_v  = (float*)alloc(256 * NB * 5);
  p.psum    = (float*)alloc(256 * NB);
  p.scores  = (float*)alloc(8);
  p.out     = (float*)d_out;

  (void)hipMemsetAsync(d_ws, 0, 64 * LSTR * 4, stream);  // zero all lines

  // r13 node structure; k_pa56 reworked (warming + vectorized P5).
  k_e0<<<dim3(256), dim3(NTHR), 0, stream>>>(p);
  for (int k = 0; k <= TI / 2; k++)
    k_e1x2<<<dim3(64), dim3(NTHR), 0, stream>>>(p, k);
  k_d0<<<dim3(64), dim3(NTHR), 0, stream>>>(p);
  for (int t = 0; t < TO; t++) {
    k_gru2<<<dim3(64), dim3(NTHR), 0, stream>>>(p, t);
    k_pa56<<<dim3(256), dim3(NTHR), 0, stream>>>(p, t);
  }
}

// Round 19
// 9179.980 us; speedup vs baseline: 1.1024x; 1.1024x over previous
//
#include <hip/hip_runtime.h>
#include <math.h>

// ---------------- problem dims ----------------
#define VV 32000
#define HH 512
#define G3 1536   // 3*HH
#define TI 128    // encoder length
#define TO 64     // max decode length
#define NB 5      // beam width
#define NEGF (-1000000000.0f)
#define NTHR 256
#define LSTR 32   // words per counter/flag line (128B)

struct Params {
  const int* seq;
  const int* sosp;
  const float *emb, *eWi, *eWh, *ebi, *ebh;
  const float *dWi, *dWh, *dbi, *dbh;
  const float *Wc, *bc, *Wout, *bout;
  unsigned* bar;
  int *cur_tok, *toks, *pars, *ptop_i;
  float *gi0, *eout, *h0b, *h1b, *dch, *cc, *ptop_v, *psum, *scores;
  float* out;
};

// relaxed agent-scope (coherence-point) ops for INTRA-kernel cross-WG data
__device__ __forceinline__ float cldf(const float* p) {
  return __hip_atomic_load(p, __ATOMIC_RELAXED, __HIP_MEMORY_SCOPE_AGENT);
}
__device__ __forceinline__ void cstf(float* p, float v) {
  __hip_atomic_store(p, v, __ATOMIC_RELAXED, __HIP_MEMORY_SCOPE_AGENT);
}
__device__ __forceinline__ int cldi(const int* p) {
  return __hip_atomic_load(p, __ATOMIC_RELAXED, __HIP_MEMORY_SCOPE_AGENT);
}
__device__ __forceinline__ void csti(int* p, int v) {
  __hip_atomic_store(p, v, __ATOMIC_RELAXED, __HIP_MEMORY_SCOPE_AGENT);
}
__device__ __forceinline__ unsigned rldu(const unsigned* p) {
  return __hip_atomic_load(p, __ATOMIC_RELAXED, __HIP_MEMORY_SCOPE_AGENT);
}
typedef unsigned long long u64t;
union F2U { u64t u; float f[2]; };
__device__ __forceinline__ void cld2(float* d, const float* p) {
  F2U x; x.u = __hip_atomic_load((const u64t*)p, __ATOMIC_RELAXED, __HIP_MEMORY_SCOPE_AGENT);
  d[0] = x.f[0]; d[1] = x.f[1];
}

__device__ __forceinline__ void bar_arrive(unsigned* lines, int myline) {
  __syncthreads();  // all this WG's sc-stores vm-drained (at CP)
  if (threadIdx.x == 0)
    __hip_atomic_fetch_add(lines + myline * LSTR, 1u,
                           __ATOMIC_RELAXED, __HIP_MEMORY_SCOPE_AGENT);
}
template <int SLP>
__device__ __forceinline__ void bar_wait8(const unsigned* lines, unsigned tgt) {
  if (threadIdx.x < 64) {
    for (;;) {
      unsigned v = tgt;
      if (threadIdx.x < 8) v = rldu(lines + threadIdx.x * LSTR);
      if (__all(v >= tgt)) break;
      __builtin_amdgcn_s_sleep(SLP);
    }
  }
  __syncthreads();
}
__device__ __forceinline__ void bcast_store(unsigned* L, int NL, unsigned tok) {
  asm volatile("s_waitcnt vmcnt(0)" ::: "memory");
  for (int i = 0; i < NL; i++)
    __hip_atomic_store(L + i * LSTR, tok, __ATOMIC_RELAXED, __HIP_MEMORY_SCOPE_AGENT);
}
template <int SLP>
__device__ __forceinline__ void leaf_wait(const unsigned* L, int grp, unsigned tok) {
  if (threadIdx.x == 0) {
    while (rldu(L + grp * LSTR) < tok) __builtin_amdgcn_s_sleep(SLP);
  }
  __syncthreads();
}

__device__ __forceinline__ float wredf(float v) {
#pragma unroll
  for (int o = 32; o; o >>= 1) v += __shfl_xor(v, o, 64);
  return v;
}

// ========== E0: wave-parallel over t (r14-validated) ==========
__global__ void __launch_bounds__(NTHR) k_e0(Params p) {
  const int wg = blockIdx.x, tid = threadIdx.x;
  const int lane = tid & 63, wv = tid >> 6;
  if (wg == 0) {
    for (int i = tid; i < 2 * HH; i += NTHR) { cstf(&p.h0b[i], 0.f); cstf(&p.h1b[i], 0.f); }
  }
  for (int lr = 0; lr < 6; lr++) {
    int row = wg * 6 + lr;
    const float* W = p.eWi + (size_t)row * HH;
    float w0[8];
#pragma unroll
    for (int j = 0; j < 8; j++) w0[j] = W[j * 64 + lane];
    float bi = p.ebi[row];
    for (int t = wv; t < TI; t += 4) {
      const float* x = p.emb + (size_t)p.seq[t] * HH;
      float s = 0.f;
#pragma unroll
      for (int j = 0; j < 8; j++) s += w0[j] * x[j * 64 + lane];
      s = wredf(s);
      if (lane == 0) p.gi0[(size_t)t * G3 + row] = s + bi;
    }
  }
}

// one encoder diagonal step (r13-validated, 64 WGs, 8 units/WG)
__device__ void enc_step(const Params& p, int T, int wg, int lane, int wv) {
  const int sIn = T & 1, sOut = sIn ^ 1;
  if (wv < 2) {
    if (T < TI) {
      float hv[8];
#pragma unroll
      for (int j = 0; j < 8; j++) hv[j] = cldf(&p.h0b[sIn * HH + j * 64 + lane]);
#pragma unroll
      for (int uu = 0; uu < 4; uu++) {
        int u = wg * 8 + wv * 4 + uu;
        float g[3];
#pragma unroll
        for (int gg = 0; gg < 3; gg++) {
          const float* W = p.eWh + (size_t)(gg * HH + u) * HH;
          float s = 0.f;
#pragma unroll
          for (int j = 0; j < 8; j++) s += W[j * 64 + lane] * hv[j];
          g[gg] = wredf(s);
        }
        if (lane == 0) {
          const float* gr = p.gi0 + (size_t)T * G3;  // plain cached (immutable)
          float ir = gr[u], iz = gr[HH + u], inn = gr[2 * HH + u];
          float hr = g[0] + p.ebh[u], hz = g[1] + p.ebh[HH + u], hn = g[2] + p.ebh[2 * HH + u];
          float r = 1.f / (1.f + expf(-(ir + hr)));
          float z = 1.f / (1.f + expf(-(iz + hz)));
          float n = tanhf(inn + r * hn);
          float hp = cldf(&p.h0b[sIn * HH + u]);
          cstf(&p.h0b[sOut * HH + u], (1.f - z) * n + z * hp);
        }
      }
    }
  } else {
    if (T >= 1) {
      float xv[8], hv[8];
#pragma unroll
      for (int j = 0; j < 8; j++) {
        xv[j] = cldf(&p.h0b[sIn * HH + j * 64 + lane]);
        hv[j] = cldf(&p.h1b[sOut * HH + j * 64 + lane]);
      }
#pragma unroll
      for (int uu = 0; uu < 4; uu++) {
        int u = wg * 8 + (wv - 2) * 4 + uu;
        float gi[3], gh[3];
#pragma unroll
        for (int gg = 0; gg < 3; gg++) {
          const float* Wi1 = p.eWi + (size_t)G3 * HH + (size_t)(gg * HH + u) * HH;
          const float* Wh1 = p.eWh + (size_t)G3 * HH + (size_t)(gg * HH + u) * HH;
          float si = 0.f, s2 = 0.f;
#pragma unroll
          for (int j = 0; j < 8; j++) { si += Wi1[j * 64 + lane] * xv[j]; s2 += Wh1[j * 64 + lane] * hv[j]; }
          gi[gg] = wredf(si);
          gh[gg] = wredf(s2);
        }
        if (lane == 0) {
          const float* bi = p.ebi + G3;
          const float* bh = p.ebh + G3;
          float ir = gi[0] + bi[u], iz = gi[1] + bi[HH + u], inn = gi[2] + bi[2 * HH + u];
          float hr = gh[0] + bh[u], hz = gh[1] + bh[HH + u], hn = gh[2] + bh[2 * HH + u];
          float r = 1.f / (1.f + expf(-(ir + hr)));
          float z = 1.f / (1.f + expf(-(iz + hz)));
          float n = tanhf(inn + r * hn);
          float hp = cldf(&p.h1b[sOut * HH + u]);
          float hnew = (1.f - z) * n + z * hp;
          cstf(&p.h1b[sIn * HH + u], hnew);
          p.eout[(size_t)(T - 1) * HH + u] = hnew;  // plain: flushed at node end
        }
      }
    }
  }
}

// node k: steps T=2k, 2k+1 with one internal leg (r13-validated)
__global__ void __launch_bounds__(NTHR) k_e1x2(Params p, int k) {
  const int wg = blockIdx.x, tid = threadIdx.x;
  const int lane = tid & 63, wv = tid >> 6;
  unsigned* ceA = p.bar + 0 * LSTR;
  enc_step(p, 2 * k, wg, lane, wv);
  if (2 * k + 1 <= TI) {
    bar_arrive(ceA, wg & 7);
    bar_wait8<2>(ceA, (unsigned)(8 * (k + 1)));
    enc_step(p, 2 * k + 1, wg, lane, wv);
  }
}

// ========== D0 (r13-validated) ==========
__global__ void __launch_bounds__(NTHR) k_d0(Params p) {
  const int wg = blockIdx.x, tid = threadIdx.x;
  for (int i = tid + wg * NTHR; i < 2 * NB * HH; i += 64 * NTHR) {
    int l = i / (NB * HH);
    int rem = i - l * (NB * HH);
    int u = rem % HH;
    p.dch[(size_t)l * NB * HH + rem] = (l == 0) ? cldf(&p.h0b[u]) : cldf(&p.h1b[u]);
  }
  if (wg == 0 && tid < NB) {
    p.cur_tok[tid] = p.sosp[0];
    p.scores[tid] = (tid == 0) ? 0.f : NEGF;
  }
}

// decoder GRU layer body on 64 WGs (r13-validated); dch via sc ops
template <int LAYER>
__device__ void gru_body(const Params& p, float* sm, int t, int ib, int ob,
                         int wg, int tid, int lane, int wv) {
  float* sx = sm;                 // [NB][HH]
  float* sh = sm + NB * HH;       // [NB][HH]
  float* fres = sm + 2 * NB * HH; // [48][NB]
  int ct[NB], pr[NB];
#pragma unroll
  for (int b = 0; b < NB; b++) {
    ct[b] = (LAYER == 0) ? cldi(&p.cur_tok[b]) : 0;
    pr[b] = (t == 0) ? b : cldi(&p.pars[(t - 1) * NB + b]);
  }
  for (int i = tid; i < NB * (HH / 2); i += NTHR) {
    int b = i >> 8, c = (i & 255) << 1;
    float x2[2], h2[2];
    if (LAYER == 0) {
      const float* e = p.emb + (size_t)ct[b] * HH + c;
      x2[0] = e[0]; x2[1] = e[1];
    } else {
      cld2(x2, &p.dch[((size_t)(ob * 2 + 0) * NB + b) * HH + c]);
    }
    cld2(h2, &p.dch[((size_t)(ib * 2 + LAYER) * NB + pr[b]) * HH + c]);
    sx[b * HH + c] = x2[0]; sx[b * HH + c + 1] = x2[1];
    sh[b * HH + c] = h2[0]; sh[b * HH + c + 1] = h2[1];
  }
  __syncthreads();
  const float* Wi = p.dWi + (size_t)LAYER * G3 * HH;
  const float* Wh = p.dWh + (size_t)LAYER * G3 * HH;
#pragma unroll
  for (int k = 0; k < 12; k++) {
    const int m_ = k % 6;
    const int f = wv * 12 + k;
    const int ul = f / 6;
    const int u = wg * 8 + ul;
    const float* W = (m_ >= 3 ? Wh : Wi) + (size_t)((m_ % 3) * HH + u) * HH;
    const float* vecb = (m_ >= 3) ? sh : sx;
    float wd[8];
#pragma unroll
    for (int j = 0; j < 8; j++) wd[j] = W[j * 64 + lane];
    float a0 = 0.f, a1 = 0.f, a2 = 0.f, a3 = 0.f, a4 = 0.f;
#pragma unroll
    for (int j = 0; j < 8; j++) {
      float wj = wd[j];
      int o = j * 64 + lane;
      a0 += wj * vecb[0 * HH + o];
      a1 += wj * vecb[1 * HH + o];
      a2 += wj * vecb[2 * HH + o];
      a3 += wj * vecb[3 * HH + o];
      a4 += wj * vecb[4 * HH + o];
    }
    float r0 = wredf(a0), r1 = wredf(a1), r2 = wredf(a2), r3 = wredf(a3), r4 = wredf(a4);
    if (lane == 0) {
      fres[f * NB + 0] = r0; fres[f * NB + 1] = r1; fres[f * NB + 2] = r2;
      fres[f * NB + 3] = r3; fres[f * NB + 4] = r4;
    }
  }
  __syncthreads();
  if (tid < 8 * NB) {
    int ul = tid / NB, b = tid - ul * NB;
    int u = wg * 8 + ul;
    const float* bi = p.dbi + LAYER * G3;
    const float* bh = p.dbh + LAYER * G3;
    float ir = fres[(ul * 6 + 0) * NB + b] + bi[u];
    float iz = fres[(ul * 6 + 1) * NB + b] + bi[HH + u];
    float inn = fres[(ul * 6 + 2) * NB + b] + bi[2 * HH + u];
    float hr = fres[(ul * 6 + 3) * NB + b] + bh[u];
    float hz = fres[(ul * 6 + 4) * NB + b] + bh[HH + u];
    float hn = fres[(ul * 6 + 5) * NB + b] + bh[2 * HH + u];
    float hp = sh[b * HH + u];
    float r = 1.f / (1.f + expf(-(ir + hr)));
    float z = 1.f / (1.f + expf(-(iz + hz)));
    float n = tanhf(inn + r * hn);
    cstf(&p.dch[((size_t)(ob * 2 + LAYER) * NB + b) * HH + u], (1.f - z) * n + z * hp);
  }
  __syncthreads();
}

// fused GRU0 + 64-WG leg + GRU1 (r13-validated)
__global__ void __launch_bounds__(NTHR) k_gru2(Params p, int t) {
  const int wg = blockIdx.x, tid = threadIdx.x;
  const int lane = tid & 63, wv = tid >> 6;
  const int ib = t & 1, ob = ib ^ 1;
  __shared__ float sm[2 * NB * HH + 48 * NB];
  unsigned* gruA = p.bar + 8 * LSTR;
  gru_body<0>(p, sm, t, ib, ob, wg, tid, lane, wv);
  bar_arrive(gruA, wg & 7);
  bar_wait8<2>(gruA, (unsigned)(8 * (t + 1)));
  gru_body<1>(p, sm, t, ib, ob, wg, tid, lane, wv);
}

// fused PA (wg<40) + leg + P5 (per-thread half-rows: max MLP) + last-man P6
__global__ void __launch_bounds__(NTHR) k_pa56(Params p, int t) {
  const int wg = blockIdx.x, tid = threadIdx.x;
  const int lane = tid & 63, wv = tid >> 6;
  const int ob = (t & 1) ^ 1;
  __shared__ float sm[4608];
  __shared__ unsigned s_mrg;
  unsigned* paA = p.bar + 16 * LSTR;  // 8
  unsigned* paF = p.bar + 24 * LSTR;  // 1
  unsigned* paL = p.bar + 32 * LSTR;  // 16
  unsigned* c5A = p.bar + 48 * LSTR;  // 8
  unsigned* c5F = p.bar + 56 * LSTR;  // 1

  if (wg < 40) {
    const int b = wg / 8, q = wg % 8;
    float* srnn = sm;            // 512
    float* sp = sm + 512;        // 128
    float* cpart = sm + 640;     // [4][512]
    float* sctx = sm + 2688;     // 512
    for (int i = tid; i < HH; i += NTHR)
      srnn[i] = cldf(&p.dch[((size_t)(ob * 2 + 1) * NB + b) * HH + i]);
    __syncthreads();
    for (int j = wv; j < TI; j += 4) {
      const float* E = p.eout + (size_t)j * HH;  // plain cached (immutable)
      float s = 0.f;
#pragma unroll
      for (int k2 = 0; k2 < 8; k2++) s += srnn[k2 * 64 + lane] * E[k2 * 64 + lane];
      s = wredf(s);
      if (lane == 0) sp[j] = s;
    }
    __syncthreads();
    if (wv == 0) {
      float v0 = sp[lane], v1 = sp[64 + lane];
      float mx = fmaxf(v0, v1);
#pragma unroll
      for (int o = 32; o; o >>= 1) mx = fmaxf(mx, __shfl_xor(mx, o, 64));
      float e0 = expf(v0 - mx), e1 = expf(v1 - mx);
      float ss = wredf(e0 + e1);
      sp[lane] = e0 / ss;
      sp[64 + lane] = e1 / ss;
    }
    __syncthreads();
    {
      float cp[8];
#pragma unroll
      for (int k2 = 0; k2 < 8; k2++) cp[k2] = 0.f;
      for (int j = wv; j < TI; j += 4) {
        float spj = sp[j];
        const float* E = p.eout + (size_t)j * HH;
#pragma unroll
        for (int k2 = 0; k2 < 8; k2++) cp[k2] += spj * E[k2 * 64 + lane];
      }
#pragma unroll
      for (int k2 = 0; k2 < 8; k2++) cpart[wv * HH + k2 * 64 + lane] = cp[k2];
    }
    __syncthreads();
    for (int i = tid; i < HH; i += NTHR)
      sctx[i] = ((cpart[0 * HH + i] + cpart[1 * HH + i]) + cpart[2 * HH + i]) + cpart[3 * HH + i];
    __syncthreads();
    for (int k = wv; k < 64; k += 4) {
      int u = q * 64 + k;
      const float* W = p.Wc + (size_t)u * (2 * HH);
      float s0 = 0.f, s1 = 0.f;
#pragma unroll
      for (int j = 0; j < 8; j++) {
        int o = j * 64 + lane;
        s0 += W[o] * srnn[o];
        s1 += W[HH + o] * sctx[o];
      }
      float r0 = wredf(s0), r1 = wredf(s1);
      if (lane == 0) cstf(&p.cc[b * HH + u], tanhf(r0 + r1 + p.bc[u]));
    }
    // last-man over PA -> bcast paL
    __syncthreads();
    if (tid == 0) {
      unsigned o1 = __hip_atomic_fetch_add(paA + (wg & 7) * LSTR, 1u,
                                           __ATOMIC_RELAXED, __HIP_MEMORY_SCOPE_AGENT);
      if (o1 == (unsigned)(5 * (t + 1) - 1)) {
        unsigned o2 = __hip_atomic_fetch_add(paF, 1u,
                                             __ATOMIC_RELAXED, __HIP_MEMORY_SCOPE_AGENT);
        if (o2 == (unsigned)(8 * (t + 1) - 1))
          bcast_store(paL, 16, (unsigned)(t + 1));
      }
    }
  }
  leaf_wait<4>(paL, wg >> 4, (unsigned)(t + 1));

  // ---- P5: 125 rows/WG; thread 2r+h owns half h of row r. 64 independent
  // float4 loads/thread (unroll 8) -> ~8KB/wave in flight, LDS-broadcast scc.
  {
    float* scc = sm;             // [NB][HH]   (0..2560)
    float* slg = sm + 2560;      // [NB][125]  (2560..3185)
    float* part = sm + 3328;     // [125][2][NB] (3328..4578)
    for (int i = tid; i < NB * (HH / 2); i += NTHR) {
      int b = i >> 8, c = (i & 255) << 1;
      float c2v[2];
      cld2(c2v, &p.cc[b * HH + c]);
      scc[b * HH + c] = c2v[0]; scc[b * HH + c + 1] = c2v[1];
    }
    __syncthreads();
    const int vbase = wg * 125;
    if (tid < 250) {
      const int r = tid >> 1, h = tid & 1;
      const float4* Wr = (const float4*)(p.Wout + (size_t)(vbase + r) * HH + h * 256);
      const float* sc0 = scc + h * 256;
      float a0 = 0.f, a1 = 0.f, a2 = 0.f, a3 = 0.f, a4 = 0.f;
#pragma unroll 8
      for (int c = 0; c < 64; c++) {
        float4 w = Wr[c];
        const float4 s0 = *(const float4*)(sc0 + 0 * HH + 4 * c);
        const float4 s1 = *(const float4*)(sc0 + 1 * HH + 4 * c);
        const float4 s2 = *(const float4*)(sc0 + 2 * HH + 4 * c);
        const float4 s3 = *(const float4*)(sc0 + 3 * HH + 4 * c);
        const float4 s4 = *(const float4*)(sc0 + 4 * HH + 4 * c);
        a0 += ((w.x * s0.x + w.y * s0.y) + (w.z * s0.z + w.w * s0.w));
        a1 += ((w.x * s1.x + w.y * s1.y) + (w.z * s1.z + w.w * s1.w));
        a2 += ((w.x * s2.x + w.y * s2.y) + (w.z * s2.z + w.w * s2.w));
        a3 += ((w.x * s3.x + w.y * s3.y) + (w.z * s3.z + w.w * s3.w));
        a4 += ((w.x * s4.x + w.y * s4.y) + (w.z * s4.z + w.w * s4.w));
      }
      float* pt = part + (size_t)tid * NB;
      pt[0] = a0; pt[1] = a1; pt[2] = a2; pt[3] = a3; pt[4] = a4;
    }
    __syncthreads();
    if (tid < 125) {
      float bo = p.bout[vbase + tid];
      const float* p0 = part + (size_t)(tid * 2) * NB;
      const float* p1 = part + (size_t)(tid * 2 + 1) * NB;
#pragma unroll
      for (int b = 0; b < NB; b++)
        slg[b * 125 + tid] = (p0[b] + p1[b]) + bo;
    }
    __syncthreads();
    if (wv == 0) {
      for (int b = 0; b < NB; b++) {
        float s0 = (lane < 125) ? expf(slg[b * 125 + lane]) : 0.f;
        float s1 = (lane + 64 < 125) ? expf(slg[b * 125 + lane + 64]) : 0.f;
        float ss = wredf(s0 + s1);
        if (lane == 0) cstf(&p.psum[wg * NB + b], ss);
      }
    } else if (wv == 1 && lane < NB) {
      int b = lane;
      float bv[5]; int bidx[5];
#pragma unroll
      for (int k = 0; k < 5; k++) { bv[k] = -INFINITY; bidx[k] = 0x7fffffff; }
      for (int r = 0; r < 125; r++) {
        float v = slg[b * 125 + r];
        if (v > bv[4]) {  // strict >: equal values keep earlier (lower) index
          int k = 4;
          while (k > 0 && v > bv[k - 1]) { bv[k] = bv[k - 1]; bidx[k] = bidx[k - 1]; k--; }
          bv[k] = v; bidx[k] = vbase + r;
        }
      }
#pragma unroll
      for (int k = 0; k < 5; k++) {
        cstf(&p.ptop_v[(wg * NB + b) * 5 + k], bv[k]);
        csti(&p.ptop_i[(wg * NB + b) * 5 + k], bidx[k]);
      }
    }
  }

  // ---- last-man selection: final P5 arriver performs the merge ----
  __syncthreads();
  if (tid == 0) {
    unsigned m = 0;
    unsigned o1 = __hip_atomic_fetch_add(c5A + (wg & 7) * LSTR, 1u,
                                         __ATOMIC_RELAXED, __HIP_MEMORY_SCOPE_AGENT);
    if (o1 == (unsigned)(32 * (t + 1) - 1)) {
      unsigned o2 = __hip_atomic_fetch_add(c5F, 1u,
                                           __ATOMIC_RELAXED, __HIP_MEMORY_SCOPE_AGENT);
      if (o2 == (unsigned)(8 * (t + 1) - 1)) m = 1;
    }
    s_mrg = m;
  }
  __syncthreads();

  // ---- P6 merge (single last-arriving WG; r10-validated algorithm) ----
  if (s_mrg) {
    float* sls = sm;               // [5]
    float* smv = sm + 8;           // [5][5]
    int* smi = (int*)(sm + 40);    // [5][5]
    for (int b = wv; b < NB; b += 4) {
      float q0 = cldf(&p.psum[(lane + 0) * NB + b]);
      float q1 = cldf(&p.psum[(lane + 64) * NB + b]);
      float q2 = cldf(&p.psum[(lane + 128) * NB + b]);
      float q3 = cldf(&p.psum[(lane + 192) * NB + b]);
      float ssum = wredf((q0 + q1) + (q2 + q3));
      float bv[5]; int bix[5];
#pragma unroll
      for (int k = 0; k < 5; k++) { bv[k] = -INFINITY; bix[k] = 0x7fffffff; }
      for (int g = 0; g < 4; g++) {
        int w = lane + g * 64;
#pragma unroll
        for (int k = 0; k < 5; k++) {
          float v = cldf(&p.ptop_v[((size_t)w * NB + b) * 5 + k]);
          int id = cldi(&p.ptop_i[((size_t)w * NB + b) * 5 + k]);
          if (v > bv[4] || (v == bv[4] && id < bix[4])) {
            int kk = 4;
            while (kk > 0 && (v > bv[kk - 1] || (v == bv[kk - 1] && id < bix[kk - 1]))) {
              bv[kk] = bv[kk - 1]; bix[kk] = bix[kk - 1]; kk--;
            }
            bv[kk] = v; bix[kk] = id;
          }
        }
      }
#pragma unroll
      for (int off = 1; off < 64; off <<= 1) {
        float ov[5]; int oi[5];
#pragma unroll
        for (int k = 0; k < 5; k++) { ov[k] = __shfl_xor(bv[k], off, 64); oi[k] = __shfl_xor(bix[k], off, 64); }
        float nv[5]; int ni[5];
        int i2 = 0, j2 = 0;
#pragma unroll
        for (int k = 0; k < 5; k++) {
          bool ta = (bv[i2] > ov[j2]) || (bv[i2] == ov[j2] && bix[i2] < oi[j2]);
          if (ta) { nv[k] = bv[i2]; ni[k] = bix[i2]; i2++; }
          else { nv[k] = ov[j2]; ni[k] = oi[j2]; j2++; }
        }
#pragma unroll
        for (int k = 0; k < 5; k++) { bv[k] = nv[k]; bix[k] = ni[k]; }
      }
      if (lane == 0) {
        sls[b] = logf(ssum);
#pragma unroll
        for (int k = 0; k < 5; k++) { smv[b * 5 + k] = bv[k]; smi[b * 5 + k] = bix[k]; }
      }
    }
    __syncthreads();
    if (tid == 0) {
      float cand[25]; int ctok[25];
      for (int b = 0; b < NB; b++) {
        float sb = cldf(&p.scores[b]), lb = sls[b];
#pragma unroll
        for (int k = 0; k < 5; k++) {
          cand[b * 5 + k] = sb + (smv[b * 5 + k] - lb);
          ctok[b * 5 + k] = smi[b * 5 + k];
        }
      }
      float s5[5]; int f5[5];
#pragma unroll
      for (int k = 0; k < 5; k++) { s5[k] = -INFINITY; f5[k] = 0x7fffffff; }
      for (int f = 0; f < 25; f++) {
        float v = cand[f];
        if (v > s5[4]) {
          int k = 4;
          while (k > 0 && v > s5[k - 1]) { s5[k] = s5[k - 1]; f5[k] = f5[k - 1]; k--; }
          s5[k] = v; f5[k] = f;
        }
      }
      for (int j2 = 0; j2 < 5; j2++) {
        int fl = f5[j2];
        csti(&p.pars[t * NB + j2], fl / 5);
        csti(&p.toks[t * NB + j2], ctok[fl]);
        csti(&p.cur_tok[j2], ctok[fl]);
      }
      for (int j2 = 0; j2 < 5; j2++) cstf(&p.scores[j2], s5[j2]);
      if (t == TO - 1) {  // final backtrack fused here
        int best = 0;
        float bvv = s5[0];
        for (int j = 1; j < NB; j++)
          if (s5[j] > bvv) { bvv = s5[j]; best = j; }
        int beam = best;
        for (int tt = TO - 1; tt >= 0; tt--) {
          p.out[tt] = (float)cldi(&p.toks[tt * NB + beam]);
          beam = cldi(&p.pars[tt * NB + beam]);
        }
        p.out[TO] = bvv;
      }
    }
  }
}

extern "C" void kernel_launch(void* const* d_in, const int* in_sizes, int n_in,
                              void* d_out, int out_size, void* d_ws, size_t ws_size,
                              hipStream_t stream) {
  (void)in_sizes; (void)n_in; (void)out_size; (void)ws_size;
  Params p;
  p.seq  = (const int*)d_in[0];
  p.sosp = (const int*)d_in[3];
  p.emb  = (const float*)d_in[4];
  p.eWi  = (const float*)d_in[5];
  p.eWh  = (const float*)d_in[6];
  p.ebi  = (const float*)d_in[7];
  p.ebh  = (const float*)d_in[8];
  p.dWi  = (const float*)d_in[9];
  p.dWh  = (const float*)d_in[10];
  p.dbi  = (const float*)d_in[11];
  p.dbh  = (const float*)d_in[12];
  p.Wc   = (const float*)d_in[13];
  p.bc   = (const float*)d_in[14];
  p.Wout = (const float*)d_in[15];
  p.bout = (const float*)d_in[16];

  char* w = (char*)d_ws;
  size_t off = 0;
  auto alloc = [&](size_t words) -> char* {
    char* r = w + off;
    off += words * 4;
    off = (off + 255) & ~(size_t)255;
    return r;
  };
  p.bar     = (unsigned*)alloc(64 * LSTR);    // counter/flag lines (memset below)
  p.cur_tok = (int*)alloc(8);
  p.toks    = (int*)alloc(TO * NB);
  p.pars    = (int*)alloc(TO * NB);
  p.ptop_i  = (int*)alloc(256 * NB * 5);
  p.gi0     = (float*)alloc((size_t)TI * G3);
  p.eout    = (float*)alloc((size_t)TI * HH);
  p.h0b     = (float*)alloc(2 * HH);
  p.h1b     = (float*)alloc(2 * HH);
  p.dch     = (float*)alloc(2 * 2 * NB * HH);
  p.cc      = (float*)alloc(NB * HH);
  p.ptop_v  = (float*)alloc(256 * NB * 5);
  p.psum    = (float*)alloc(256 * NB);
  p.scores  = (float*)alloc(8);
  p.out     = (float*)d_out;

  (void)hipMemsetAsync(d_ws, 0, 64 * LSTR * 4, stream);  // zero all lines

  // r13 node structure; P5 restructured for memory-level parallelism.
  k_e0<<<dim3(256), dim3(NTHR), 0, stream>>>(p);
  for (int k = 0; k <= TI / 2; k++)
    k_e1x2<<<dim3(64), dim3(NTHR), 0, stream>>>(p, k);
  k_d0<<<dim3(64), dim3(NTHR), 0, stream>>>(p);
  for (int t = 0; t < TO; t++) {
    k_gru2<<<dim3(64), dim3(NTHR), 0, stream>>>(p, t);
    k_pa56<<<dim3(256), dim3(NTHR), 0, stream>>>(p, t);
  }
}

// Round 20
// 7021.942 us; speedup vs baseline: 1.4412x; 1.3073x over previous
//
#include <hip/hip_runtime.h>
#include <math.h>

// ---------------- problem dims ----------------
#define VV 32000
#define HH 512
#define G3 1536   // 3*HH
#define TI 128    // encoder length
#define TO 64     // max decode length
#define NB 5      // beam width
#define NEGF (-1000000000.0f)
#define NTHR 256
#define NT5 512   // k_pa56 block size (8 waves/CU)
#define LSTR 32   // words per counter/flag line (128B)

struct Params {
  const int* seq;
  const int* sosp;
  const float *emb, *eWi, *eWh, *ebi, *ebh;
  const float *dWi, *dWh, *dbi, *dbh;
  const float *Wc, *bc, *Wout, *bout;
  unsigned* bar;
  int *cur_tok, *toks, *pars, *ptop_i;
  float *gi0, *eout, *h0b, *h1b, *dch, *cc, *ptop_v, *psum, *scores;
  float* out;
};

// relaxed agent-scope (coherence-point) ops for INTRA-kernel cross-WG data
__device__ __forceinline__ float cldf(const float* p) {
  return __hip_atomic_load(p, __ATOMIC_RELAXED, __HIP_MEMORY_SCOPE_AGENT);
}
__device__ __forceinline__ void cstf(float* p, float v) {
  __hip_atomic_store(p, v, __ATOMIC_RELAXED, __HIP_MEMORY_SCOPE_AGENT);
}
__device__ __forceinline__ int cldi(const int* p) {
  return __hip_atomic_load(p, __ATOMIC_RELAXED, __HIP_MEMORY_SCOPE_AGENT);
}
__device__ __forceinline__ void csti(int* p, int v) {
  __hip_atomic_store(p, v, __ATOMIC_RELAXED, __HIP_MEMORY_SCOPE_AGENT);
}
__device__ __forceinline__ unsigned rldu(const unsigned* p) {
  return __hip_atomic_load(p, __ATOMIC_RELAXED, __HIP_MEMORY_SCOPE_AGENT);
}
typedef unsigned long long u64t;
union F2U { u64t u; float f[2]; };
__device__ __forceinline__ void cld2(float* d, const float* p) {
  F2U x; x.u = __hip_atomic_load((const u64t*)p, __ATOMIC_RELAXED, __HIP_MEMORY_SCOPE_AGENT);
  d[0] = x.f[0]; d[1] = x.f[1];
}

__device__ __forceinline__ void bar_arrive(unsigned* lines, int myline) {
  __syncthreads();  // all this WG's sc-stores vm-drained (at CP)
  if (threadIdx.x == 0)
    __hip_atomic_fetch_add(lines + myline * LSTR, 1u,
                           __ATOMIC_RELAXED, __HIP_MEMORY_SCOPE_AGENT);
}
template <int SLP>
__device__ __forceinline__ void bar_wait8(const unsigned* lines, unsigned tgt) {
  if (threadIdx.x < 64) {
    for (;;) {
      unsigned v = tgt;
      if (threadIdx.x < 8) v = rldu(lines + threadIdx.x * LSTR);
      if (__all(v >= tgt)) break;
      __builtin_amdgcn_s_sleep(SLP);
    }
  }
  __syncthreads();
}
__device__ __forceinline__ void bcast_store(unsigned* L, int NL, unsigned tok) {
  asm volatile("s_waitcnt vmcnt(0)" ::: "memory");
  for (int i = 0; i < NL; i++)
    __hip_atomic_store(L + i * LSTR, tok, __ATOMIC_RELAXED, __HIP_MEMORY_SCOPE_AGENT);
}
template <int SLP>
__device__ __forceinline__ void leaf_wait(const unsigned* L, int grp, unsigned tok) {
  if (threadIdx.x == 0) {
    while (rldu(L + grp * LSTR) < tok) __builtin_amdgcn_s_sleep(SLP);
  }
  __syncthreads();
}

__device__ __forceinline__ float wredf(float v) {
#pragma unroll
  for (int o = 32; o; o >>= 1) v += __shfl_xor(v, o, 64);
  return v;
}

// ========== E0: wave-parallel over t (r14-validated) ==========
__global__ void __launch_bounds__(NTHR) k_e0(Params p) {
  const int wg = blockIdx.x, tid = threadIdx.x;
  const int lane = tid & 63, wv = tid >> 6;
  if (wg == 0) {
    for (int i = tid; i < 2 * HH; i += NTHR) { cstf(&p.h0b[i], 0.f); cstf(&p.h1b[i], 0.f); }
  }
  for (int lr = 0; lr < 6; lr++) {
    int row = wg * 6 + lr;
    const float* W = p.eWi + (size_t)row * HH;
    float w0[8];
#pragma unroll
    for (int j = 0; j < 8; j++) w0[j] = W[j * 64 + lane];
    float bi = p.ebi[row];
    for (int t = wv; t < TI; t += 4) {
      const float* x = p.emb + (size_t)p.seq[t] * HH;
      float s = 0.f;
#pragma unroll
      for (int j = 0; j < 8; j++) s += w0[j] * x[j * 64 + lane];
      s = wredf(s);
      if (lane == 0) p.gi0[(size_t)t * G3 + row] = s + bi;
    }
  }
}

// one encoder diagonal step (r13-validated, 64 WGs, 8 units/WG)
__device__ void enc_step(const Params& p, int T, int wg, int lane, int wv) {
  const int sIn = T & 1, sOut = sIn ^ 1;
  if (wv < 2) {
    if (T < TI) {
      float hv[8];
#pragma unroll
      for (int j = 0; j < 8; j++) hv[j] = cldf(&p.h0b[sIn * HH + j * 64 + lane]);
#pragma unroll
      for (int uu = 0; uu < 4; uu++) {
        int u = wg * 8 + wv * 4 + uu;
        float g[3];
#pragma unroll
        for (int gg = 0; gg < 3; gg++) {
          const float* W = p.eWh + (size_t)(gg * HH + u) * HH;
          float s = 0.f;
#pragma unroll
          for (int j = 0; j < 8; j++) s += W[j * 64 + lane] * hv[j];
          g[gg] = wredf(s);
        }
        if (lane == 0) {
          const float* gr = p.gi0 + (size_t)T * G3;  // plain cached (immutable)
          float ir = gr[u], iz = gr[HH + u], inn = gr[2 * HH + u];
          float hr = g[0] + p.ebh[u], hz = g[1] + p.ebh[HH + u], hn = g[2] + p.ebh[2 * HH + u];
          float r = 1.f / (1.f + expf(-(ir + hr)));
          float z = 1.f / (1.f + expf(-(iz + hz)));
          float n = tanhf(inn + r * hn);
          float hp = cldf(&p.h0b[sIn * HH + u]);
          cstf(&p.h0b[sOut * HH + u], (1.f - z) * n + z * hp);
        }
      }
    }
  } else {
    if (T >= 1) {
      float xv[8], hv[8];
#pragma unroll
      for (int j = 0; j < 8; j++) {
        xv[j] = cldf(&p.h0b[sIn * HH + j * 64 + lane]);
        hv[j] = cldf(&p.h1b[sOut * HH + j * 64 + lane]);
      }
#pragma unroll
      for (int uu = 0; uu < 4; uu++) {
        int u = wg * 8 + (wv - 2) * 4 + uu;
        float gi[3], gh[3];
#pragma unroll
        for (int gg = 0; gg < 3; gg++) {
          const float* Wi1 = p.eWi + (size_t)G3 * HH + (size_t)(gg * HH + u) * HH;
          const float* Wh1 = p.eWh + (size_t)G3 * HH + (size_t)(gg * HH + u) * HH;
          float si = 0.f, s2 = 0.f;
#pragma unroll
          for (int j = 0; j < 8; j++) { si += Wi1[j * 64 + lane] * xv[j]; s2 += Wh1[j * 64 + lane] * hv[j]; }
          gi[gg] = wredf(si);
          gh[gg] = wredf(s2);
        }
        if (lane == 0) {
          const float* bi = p.ebi + G3;
          const float* bh = p.ebh + G3;
          float ir = gi[0] + bi[u], iz = gi[1] + bi[HH + u], inn = gi[2] + bi[2 * HH + u];
          float hr = gh[0] + bh[u], hz = gh[1] + bh[HH + u], hn = gh[2] + bh[2 * HH + u];
          float r = 1.f / (1.f + expf(-(ir + hr)));
          float z = 1.f / (1.f + expf(-(iz + hz)));
          float n = tanhf(inn + r * hn);
          float hp = cldf(&p.h1b[sOut * HH + u]);
          float hnew = (1.f - z) * n + z * hp;
          cstf(&p.h1b[sIn * HH + u], hnew);
          p.eout[(size_t)(T - 1) * HH + u] = hnew;  // plain: flushed at node end
        }
      }
    }
  }
}

// node k: steps T=2k, 2k+1 with one internal leg (r13-validated)
__global__ void __launch_bounds__(NTHR) k_e1x2(Params p, int k) {
  const int wg = blockIdx.x, tid = threadIdx.x;
  const int lane = tid & 63, wv = tid >> 6;
  unsigned* ceA = p.bar + 0 * LSTR;
  enc_step(p, 2 * k, wg, lane, wv);
  if (2 * k + 1 <= TI) {
    bar_arrive(ceA, wg & 7);
    bar_wait8<2>(ceA, (unsigned)(8 * (k + 1)));
    enc_step(p, 2 * k + 1, wg, lane, wv);
  }
}

// ========== D0 (r13-validated) ==========
__global__ void __launch_bounds__(NTHR) k_d0(Params p) {
  const int wg = blockIdx.x, tid = threadIdx.x;
  for (int i = tid + wg * NTHR; i < 2 * NB * HH; i += 64 * NTHR) {
    int l = i / (NB * HH);
    int rem = i - l * (NB * HH);
    int u = rem % HH;
    p.dch[(size_t)l * NB * HH + rem] = (l == 0) ? cldf(&p.h0b[u]) : cldf(&p.h1b[u]);
  }
  if (wg == 0 && tid < NB) {
    p.cur_tok[tid] = p.sosp[0];
    p.scores[tid] = (tid == 0) ? 0.f : NEGF;
  }
}

// decoder GRU layer body on 64 WGs (r13-validated); dch via sc ops
template <int LAYER>
__device__ void gru_body(const Params& p, float* sm, int t, int ib, int ob,
                         int wg, int tid, int lane, int wv) {
  float* sx = sm;                 // [NB][HH]
  float* sh = sm + NB * HH;       // [NB][HH]
  float* fres = sm + 2 * NB * HH; // [48][NB]
  int ct[NB], pr[NB];
#pragma unroll
  for (int b = 0; b < NB; b++) {
    ct[b] = (LAYER == 0) ? cldi(&p.cur_tok[b]) : 0;
    pr[b] = (t == 0) ? b : cldi(&p.pars[(t - 1) * NB + b]);
  }
  for (int i = tid; i < NB * (HH / 2); i += NTHR) {
    int b = i >> 8, c = (i & 255) << 1;
    float x2[2], h2[2];
    if (LAYER == 0) {
      const float* e = p.emb + (size_t)ct[b] * HH + c;
      x2[0] = e[0]; x2[1] = e[1];
    } else {
      cld2(x2, &p.dch[((size_t)(ob * 2 + 0) * NB + b) * HH + c]);
    }
    cld2(h2, &p.dch[((size_t)(ib * 2 + LAYER) * NB + pr[b]) * HH + c]);
    sx[b * HH + c] = x2[0]; sx[b * HH + c + 1] = x2[1];
    sh[b * HH + c] = h2[0]; sh[b * HH + c + 1] = h2[1];
  }
  __syncthreads();
  const float* Wi = p.dWi + (size_t)LAYER * G3 * HH;
  const float* Wh = p.dWh + (size_t)LAYER * G3 * HH;
#pragma unroll
  for (int k = 0; k < 12; k++) {
    const int m_ = k % 6;
    const int f = wv * 12 + k;
    const int ul = f / 6;
    const int u = wg * 8 + ul;
    const float* W = (m_ >= 3 ? Wh : Wi) + (size_t)((m_ % 3) * HH + u) * HH;
    const float* vecb = (m_ >= 3) ? sh : sx;
    float wd[8];
#pragma unroll
    for (int j = 0; j < 8; j++) wd[j] = W[j * 64 + lane];
    float a0 = 0.f, a1 = 0.f, a2 = 0.f, a3 = 0.f, a4 = 0.f;
#pragma unroll
    for (int j = 0; j < 8; j++) {
      float wj = wd[j];
      int o = j * 64 + lane;
      a0 += wj * vecb[0 * HH + o];
      a1 += wj * vecb[1 * HH + o];
      a2 += wj * vecb[2 * HH + o];
      a3 += wj * vecb[3 * HH + o];
      a4 += wj * vecb[4 * HH + o];
    }
    float r0 = wredf(a0), r1 = wredf(a1), r2 = wredf(a2), r3 = wredf(a3), r4 = wredf(a4);
    if (lane == 0) {
      fres[f * NB + 0] = r0; fres[f * NB + 1] = r1; fres[f * NB + 2] = r2;
      fres[f * NB + 3] = r3; fres[f * NB + 4] = r4;
    }
  }
  __syncthreads();
  if (tid < 8 * NB) {
    int ul = tid / NB, b = tid - ul * NB;
    int u = wg * 8 + ul;
    const float* bi = p.dbi + LAYER * G3;
    const float* bh = p.dbh + LAYER * G3;
    float ir = fres[(ul * 6 + 0) * NB + b] + bi[u];
    float iz = fres[(ul * 6 + 1) * NB + b] + bi[HH + u];
    float inn = fres[(ul * 6 + 2) * NB + b] + bi[2 * HH + u];
    float hr = fres[(ul * 6 + 3) * NB + b] + bh[u];
    float hz = fres[(ul * 6 + 4) * NB + b] + bh[HH + u];
    float hn = fres[(ul * 6 + 5) * NB + b] + bh[2 * HH + u];
    float hp = sh[b * HH + u];
    float r = 1.f / (1.f + expf(-(ir + hr)));
    float z = 1.f / (1.f + expf(-(iz + hz)));
    float n = tanhf(inn + r * hn);
    cstf(&p.dch[((size_t)(ob * 2 + LAYER) * NB + b) * HH + u], (1.f - z) * n + z * hp);
  }
  __syncthreads();
}

// fused GRU0 + 64-WG leg + GRU1 (r13-validated)
__global__ void __launch_bounds__(NTHR) k_gru2(Params p, int t) {
  const int wg = blockIdx.x, tid = threadIdx.x;
  const int lane = tid & 63, wv = tid >> 6;
  const int ib = t & 1, ob = ib ^ 1;
  __shared__ float sm[2 * NB * HH + 48 * NB];
  unsigned* gruA = p.bar + 8 * LSTR;
  gru_body<0>(p, sm, t, ib, ob, wg, tid, lane, wv);
  bar_arrive(gruA, wg & 7);
  bar_wait8<2>(gruA, (unsigned)(8 * (t + 1)));
  gru_body<1>(p, sm, t, ib, ob, wg, tid, lane, wv);
}

// fused PA (wg<40, 8 waves) + leg + P5 (quarter-rows, broadcast scc) + P6
__global__ void __launch_bounds__(NT5) k_pa56(Params p, int t) {
  const int wg = blockIdx.x, tid = threadIdx.x;
  const int lane = tid & 63, wv = tid >> 6;   // wv in [0,8)
  const int ob = (t & 1) ^ 1;
  __shared__ float sm[5760];
  __shared__ unsigned s_mrg;
  unsigned* paA = p.bar + 16 * LSTR;  // 8
  unsigned* paF = p.bar + 24 * LSTR;  // 1
  unsigned* paL = p.bar + 32 * LSTR;  // 16
  unsigned* c5A = p.bar + 48 * LSTR;  // 8
  unsigned* c5F = p.bar + 56 * LSTR;  // 1

  if (wg < 40) {
    const int b = wg / 8, q = wg % 8;
    float* srnn = sm;            // 512
    float* sp = sm + 512;        // 128
    float* cpart = sm + 640;     // [8][512]
    float* sctx = sm + 4736;     // 512
    for (int i = tid; i < HH; i += NT5)
      srnn[i] = cldf(&p.dch[((size_t)(ob * 2 + 1) * NB + b) * HH + i]);
    __syncthreads();
    // per-j dot is wave-internal with the SAME lane mapping as r13 -> sp[j]
    // bitwise identical; only the j->wave assignment changed (mod 8).
    for (int j = wv; j < TI; j += 8) {
      const float* E = p.eout + (size_t)j * HH;  // plain cached (immutable)
      float s = 0.f;
#pragma unroll
      for (int k2 = 0; k2 < 8; k2++) s += srnn[k2 * 64 + lane] * E[k2 * 64 + lane];
      s = wredf(s);
      if (lane == 0) sp[j] = s;
    }
    __syncthreads();
    if (wv == 0) {
      float v0 = sp[lane], v1 = sp[64 + lane];
      float mx = fmaxf(v0, v1);
#pragma unroll
      for (int o = 32; o; o >>= 1) mx = fmaxf(mx, __shfl_xor(mx, o, 64));
      float e0 = expf(v0 - mx), e1 = expf(v1 - mx);
      float ss = wredf(e0 + e1);
      sp[lane] = e0 / ss;
      sp[64 + lane] = e1 / ss;
    }
    __syncthreads();
    {  // ctx: 8 wave-partials (combine order fixed; ~ulp shift vs r19, OK)
      float cp[8];
#pragma unroll
      for (int k2 = 0; k2 < 8; k2++) cp[k2] = 0.f;
      for (int j = wv; j < TI; j += 8) {
        float spj = sp[j];
        const float* E = p.eout + (size_t)j * HH;
#pragma unroll
        for (int k2 = 0; k2 < 8; k2++) cp[k2] += spj * E[k2 * 64 + lane];
      }
#pragma unroll
      for (int k2 = 0; k2 < 8; k2++) cpart[wv * HH + k2 * 64 + lane] = cp[k2];
    }
    __syncthreads();
    for (int i = tid; i < HH; i += NT5)
      sctx[i] = ((cpart[0 * HH + i] + cpart[1 * HH + i]) + (cpart[2 * HH + i] + cpart[3 * HH + i]))
              + ((cpart[4 * HH + i] + cpart[5 * HH + i]) + (cpart[6 * HH + i] + cpart[7 * HH + i]));
    __syncthreads();
    for (int k = wv; k < 64; k += 8) {
      int u = q * 64 + k;
      const float* W = p.Wc + (size_t)u * (2 * HH);
      float s0 = 0.f, s1 = 0.f;
#pragma unroll
      for (int j = 0; j < 8; j++) {
        int o = j * 64 + lane;
        s0 += W[o] * srnn[o];
        s1 += W[HH + o] * sctx[o];
      }
      float r0 = wredf(s0), r1 = wredf(s1);
      if (lane == 0) cstf(&p.cc[b * HH + u], tanhf(r0 + r1 + p.bc[u]));
    }
    // last-man over PA -> bcast paL
    __syncthreads();
    if (tid == 0) {
      unsigned o1 = __hip_atomic_fetch_add(paA + (wg & 7) * LSTR, 1u,
                                           __ATOMIC_RELAXED, __HIP_MEMORY_SCOPE_AGENT);
      if (o1 == (unsigned)(5 * (t + 1) - 1)) {
        unsigned o2 = __hip_atomic_fetch_add(paF, 1u,
                                             __ATOMIC_RELAXED, __HIP_MEMORY_SCOPE_AGENT);
        if (o2 == (unsigned)(8 * (t + 1) - 1))
          bcast_store(paL, 16, (unsigned)(t + 1));
      }
    }
  }
  leaf_wait<4>(paL, wg >> 4, (unsigned)(t + 1));

  // ---- P5: 125 rows/WG; thread q*125+r owns quarter q of row r.
  // 32 independent float4 loads/thread; scc LDS reads are same-address
  // broadcasts within a wave (q uniform across lanes) -> conflict-free.
  {
    float* scc = sm;             // [NB][HH]     (0..2560)
    float* slg = sm + 2560;      // [NB][125]    (2560..3185)
    float* part = sm + 3200;     // [500][NB]    (3200..5700)
    for (int i = tid; i < NB * (HH / 2); i += NT5) {
      int b = i >> 8, c = (i & 255) << 1;
      float c2v[2];
      cld2(c2v, &p.cc[b * HH + c]);
      scc[b * HH + c] = c2v[0]; scc[b * HH + c + 1] = c2v[1];
    }
    __syncthreads();
    const int vbase = wg * 125;
    if (tid < 500) {
      const int q = tid / 125, r = tid - q * 125;
      const float4* Wr = (const float4*)(p.Wout + (size_t)(vbase + r) * HH + q * 128);
      const float* sc0 = scc + q * 128;
      float a0 = 0.f, a1 = 0.f, a2 = 0.f, a3 = 0.f, a4 = 0.f;
#pragma unroll 8
      for (int c = 0; c < 32; c++) {
        float4 w = Wr[c];
        const float4 s0 = *(const float4*)(sc0 + 0 * HH + 4 * c);
        const float4 s1 = *(const float4*)(sc0 + 1 * HH + 4 * c);
        const float4 s2 = *(const float4*)(sc0 + 2 * HH + 4 * c);
        const float4 s3 = *(const float4*)(sc0 + 3 * HH + 4 * c);
        const float4 s4 = *(const float4*)(sc0 + 4 * HH + 4 * c);
        a0 += ((w.x * s0.x + w.y * s0.y) + (w.z * s0.z + w.w * s0.w));
        a1 += ((w.x * s1.x + w.y * s1.y) + (w.z * s1.z + w.w * s1.w));
        a2 += ((w.x * s2.x + w.y * s2.y) + (w.z * s2.z + w.w * s2.w));
        a3 += ((w.x * s3.x + w.y * s3.y) + (w.z * s3.z + w.w * s3.w));
        a4 += ((w.x * s4.x + w.y * s4.y) + (w.z * s4.z + w.w * s4.w));
      }
      float* pt = part + (size_t)tid * NB;
      pt[0] = a0; pt[1] = a1; pt[2] = a2; pt[3] = a3; pt[4] = a4;
    }
    __syncthreads();
    if (tid < 125) {
      float bo = p.bout[vbase + tid];
      const float* p0 = part + (size_t)(0 * 125 + tid) * NB;
      const float* p1 = part + (size_t)(1 * 125 + tid) * NB;
      const float* p2 = part + (size_t)(2 * 125 + tid) * NB;
      const float* p3 = part + (size_t)(3 * 125 + tid) * NB;
#pragma unroll
      for (int b = 0; b < NB; b++)
        slg[b * 125 + tid] = ((p0[b] + p1[b]) + (p2[b] + p3[b])) + bo;
    }
    __syncthreads();
    if (wv == 0) {
      for (int b = 0; b < NB; b++) {
        float s0 = (lane < 125) ? expf(slg[b * 125 + lane]) : 0.f;
        float s1 = (lane + 64 < 125) ? expf(slg[b * 125 + lane + 64]) : 0.f;
        float ss = wredf(s0 + s1);
        if (lane == 0) cstf(&p.psum[wg * NB + b], ss);
      }
    } else if (wv == 1 && lane < NB) {
      int b = lane;
      float bv[5]; int bidx[5];
#pragma unroll
      for (int k = 0; k < 5; k++) { bv[k] = -INFINITY; bidx[k] = 0x7fffffff; }
      for (int r = 0; r < 125; r++) {
        float v = slg[b * 125 + r];
        if (v > bv[4]) {  // strict >: equal values keep earlier (lower) index
          int k = 4;
          while (k > 0 && v > bv[k - 1]) { bv[k] = bv[k - 1]; bidx[k] = bidx[k - 1]; k--; }
          bv[k] = v; bidx[k] = vbase + r;
        }
      }
#pragma unroll
      for (int k = 0; k < 5; k++) {
        cstf(&p.ptop_v[(wg * NB + b) * 5 + k], bv[k]);
        csti(&p.ptop_i[(wg * NB + b) * 5 + k], bidx[k]);
      }
    }
  }

  // ---- last-man selection: final P5 arriver performs the merge ----
  __syncthreads();
  if (tid == 0) {
    unsigned m = 0;
    unsigned o1 = __hip_atomic_fetch_add(c5A + (wg & 7) * LSTR, 1u,
                                         __ATOMIC_RELAXED, __HIP_MEMORY_SCOPE_AGENT);
    if (o1 == (unsigned)(32 * (t + 1) - 1)) {
      unsigned o2 = __hip_atomic_fetch_add(c5F, 1u,
                                           __ATOMIC_RELAXED, __HIP_MEMORY_SCOPE_AGENT);
      if (o2 == (unsigned)(8 * (t + 1) - 1)) m = 1;
    }
    s_mrg = m;
  }
  __syncthreads();

  // ---- P6 merge (single last-arriving WG; r10-validated, b stride 8) ----
  if (s_mrg) {
    float* sls = sm;               // [5]
    float* smv = sm + 8;           // [5][5]
    int* smi = (int*)(sm + 40);    // [5][5]
    for (int b = wv; b < NB; b += 8) {
      float q0 = cldf(&p.psum[(lane + 0) * NB + b]);
      float q1 = cldf(&p.psum[(lane + 64) * NB + b]);
      float q2 = cldf(&p.psum[(lane + 128) * NB + b]);
      float q3 = cldf(&p.psum[(lane + 192) * NB + b]);
      float ssum = wredf((q0 + q1) + (q2 + q3));
      float bv[5]; int bix[5];
#pragma unroll
      for (int k = 0; k < 5; k++) { bv[k] = -INFINITY; bix[k] = 0x7fffffff; }
      for (int g = 0; g < 4; g++) {
        int w = lane + g * 64;
#pragma unroll
        for (int k = 0; k < 5; k++) {
          float v = cldf(&p.ptop_v[((size_t)w * NB + b) * 5 + k]);
          int id = cldi(&p.ptop_i[((size_t)w * NB + b) * 5 + k]);
          if (v > bv[4] || (v == bv[4] && id < bix[4])) {
            int kk = 4;
            while (kk > 0 && (v > bv[kk - 1] || (v == bv[kk - 1] && id < bix[kk - 1]))) {
              bv[kk] = bv[kk - 1]; bix[kk] = bix[kk - 1]; kk--;
            }
            bv[kk] = v; bix[kk] = id;
          }
        }
      }
#pragma unroll
      for (int off = 1; off < 64; off <<= 1) {
        float ov[5]; int oi[5];
#pragma unroll
        for (int k = 0; k < 5; k++) { ov[k] = __shfl_xor(bv[k], off, 64); oi[k] = __shfl_xor(bix[k], off, 64); }
        float nv[5]; int ni[5];
        int i2 = 0, j2 = 0;
#pragma unroll
        for (int k = 0; k < 5; k++) {
          bool ta = (bv[i2] > ov[j2]) || (bv[i2] == ov[j2] && bix[i2] < oi[j2]);
          if (ta) { nv[k] = bv[i2]; ni[k] = bix[i2]; i2++; }
          else { nv[k] = ov[j2]; ni[k] = oi[j2]; j2++; }
        }
#pragma unroll
        for (int k = 0; k < 5; k++) { bv[k] = nv[k]; bix[k] = ni[k]; }
      }
      if (lane == 0) {
        sls[b] = logf(ssum);
#pragma unroll
        for (int k = 0; k < 5; k++) { smv[b * 5 + k] = bv[k]; smi[b * 5 + k] = bix[k]; }
      }
    }
    __syncthreads();
    if (tid == 0) {
      float cand[25]; int ctok[25];
      for (int b = 0; b < NB; b++) {
        float sb = cldf(&p.scores[b]), lb = sls[b];
#pragma unroll
        for (int k = 0; k < 5; k++) {
          cand[b * 5 + k] = sb + (smv[b * 5 + k] - lb);
          ctok[b * 5 + k] = smi[b * 5 + k];
        }
      }
      float s5[5]; int f5[5];
#pragma unroll
      for (int k = 0; k < 5; k++) { s5[k] = -INFINITY; f5[k] = 0x7fffffff; }
      for (int f = 0; f < 25; f++) {
        float v = cand[f];
        if (v > s5[4]) {
          int k = 4;
          while (k > 0 && v > s5[k - 1]) { s5[k] = s5[k - 1]; f5[k] = f5[k - 1]; k--; }
          s5[k] = v; f5[k] = f;
        }
      }
      for (int j2 = 0; j2 < 5; j2++) {
        int fl = f5[j2];
        csti(&p.pars[t * NB + j2], fl / 5);
        csti(&p.toks[t * NB + j2], ctok[fl]);
        csti(&p.cur_tok[j2], ctok[fl]);
      }
      for (int j2 = 0; j2 < 5; j2++) cstf(&p.scores[j2], s5[j2]);
      if (t == TO - 1) {  // final backtrack fused here
        int best = 0;
        float bvv = s5[0];
        for (int j = 1; j < NB; j++)
          if (s5[j] > bvv) { bvv = s5[j]; best = j; }
        int beam = best;
        for (int tt = TO - 1; tt >= 0; tt--) {
          p.out[tt] = (float)cldi(&p.toks[tt * NB + beam]);
          beam = cldi(&p.pars[tt * NB + beam]);
        }
        p.out[TO] = bvv;
      }
    }
  }
}

extern "C" void kernel_launch(void* const* d_in, const int* in_sizes, int n_in,
                              void* d_out, int out_size, void* d_ws, size_t ws_size,
                              hipStream_t stream) {
  (void)in_sizes; (void)n_in; (void)out_size; (void)ws_size;
  Params p;
  p.seq  = (const int*)d_in[0];
  p.sosp = (const int*)d_in[3];
  p.emb  = (const float*)d_in[4];
  p.eWi  = (const float*)d_in[5];
  p.eWh  = (const float*)d_in[6];
  p.ebi  = (const float*)d_in[7];
  p.ebh  = (const float*)d_in[8];
  p.dWi  = (const float*)d_in[9];
  p.dWh  = (const float*)d_in[10];
  p.dbi  = (const float*)d_in[11];
  p.dbh  = (const float*)d_in[12];
  p.Wc   = (const float*)d_in[13];
  p.bc   = (const float*)d_in[14];
  p.Wout = (const float*)d_in[15];
  p.bout = (const float*)d_in[16];

  char* w = (char*)d_ws;
  size_t off = 0;
  auto alloc = [&](size_t words) -> char* {
    char* r = w + off;
    off += words * 4;
    off = (off + 255) & ~(size_t)255;
    return r;
  };
  p.bar     = (unsigned*)alloc(64 * LSTR);    // counter/flag lines (memset below)
  p.cur_tok = (int*)alloc(8);
  p.toks    = (int*)alloc(TO * NB);
  p.pars    = (int*)alloc(TO * NB);
  p.ptop_i  = (int*)alloc(256 * NB * 5);
  p.gi0     = (float*)alloc((size_t)TI * G3);
  p.eout    = (float*)alloc((size_t)TI * HH);
  p.h0b     = (float*)alloc(2 * HH);
  p.h1b     = (float*)alloc(2 * HH);
  p.dch     = (float*)alloc(2 * 2 * NB * HH);
  p.cc      = (float*)alloc(NB * HH);
  p.ptop_v  = (float*)alloc(256 * NB * 5);
  p.psum    = (float*)alloc(256 * NB);
  p.scores  = (float*)alloc(8);
  p.out     = (float*)d_out;

  (void)hipMemsetAsync(d_ws, 0, 64 * LSTR * 4, stream);  // zero all lines

  // r13 node structure; P5 quarter-row layout at 512 threads (8 waves/CU).
  k_e0<<<dim3(256), dim3(NTHR), 0, stream>>>(p);
  for (int k = 0; k <= TI / 2; k++)
    k_e1x2<<<dim3(64), dim3(NTHR), 0, stream>>>(p, k);
  k_d0<<<dim3(64), dim3(NTHR), 0, stream>>>(p);
  for (int t = 0; t < TO; t++) {
    k_gru2<<<dim3(64), dim3(NTHR), 0, stream>>>(p, t);
    k_pa56<<<dim3(256), dim3(NT5), 0, stream>>>(p, t);
  }
}